// Round 6
// baseline (219.258 us; speedup 1.0000x reference)
//
#include <hip/hip_runtime.h>
#include <stdint.h>

// ---------------------------------------------------------------------------
// DualGatedRecurrence on MI355X.
// fwht() in the reference is the identity for D=1024 (butterfly S: S^2=2I;
// 10 steps = 32*I, cancelled by d^-0.5) => hproj(x,s) = x * prod_i(s_i).
// Pipeline (4 dispatches):
//   scanA+prep: per-chunk local scans (64 chunks of 32 t-steps, d2-vector).
//     PRELOAD-ALL pattern: all 32 x-loads issued before any store so the
//     load pipeline stays deep (loads/stores share the in-order vmcnt FIFO
//     on CDNA — interleaving serializes it, the R4/R5 scan pathology).
//     Emits P,H chunk aggregates + xb (bf16 x). Prep blocks convert weights
//     to bf16 and zero rowsum.
//   scanC: carry prefix from P/H (L2-resident) + rescan from bf16 xb
//     (preload-all again) -> hcat = [fast_h | slow_h] bf16.
//   GEMM1: 16x16x32 bf16 MFMA, BK=64, XOR-swizzled LDS (conflict-free,
//     verified R3+), XCD-aware remap (verified R4: FETCH 86->44 MB);
//     epilogue sigmoid*hcat + fused row sum-of-squares atomics.
//   GEMM2: same structure, rsqrt row-scale epilogue.
// ---------------------------------------------------------------------------

typedef __attribute__((ext_vector_type(8))) short short8;     // 8 bf16
typedef __attribute__((ext_vector_type(4))) float f32x4;
typedef __attribute__((ext_vector_type(2))) float f32x2;
typedef __attribute__((ext_vector_type(4))) unsigned short ushort4v;
typedef __attribute__((ext_vector_type(2))) unsigned short ushort2v;

typedef const __attribute__((address_space(1))) unsigned int* as1_u32p;
typedef __attribute__((address_space(3))) unsigned int* as3_u32p;

__device__ __forceinline__ void cp16(const void* g, void* l) {
  __builtin_amdgcn_global_load_lds((as1_u32p)(uintptr_t)g,
                                   (as3_u32p)(unsigned int)(uintptr_t)l,
                                   16, 0, 0);
}

__device__ __forceinline__ float b2f(unsigned short h) {
  union { unsigned int u; float f; } v; v.u = ((unsigned int)h) << 16; return v.f;
}
__device__ __forceinline__ unsigned short f2b(float f) {
  union { float f; unsigned int u; } v; v.f = f;
  unsigned int r = v.u + 0x7fffu + ((v.u >> 16) & 1u);   // round-nearest-even
  return (unsigned short)(r >> 16);
}
// fast sigmoid: hw exp + hw rcp
__device__ __forceinline__ float sigmoidf_(float z) {
  return __builtin_amdgcn_rcpf(1.0f + __expf(-z));
}

// ---------------- scanA (blocks 0..511) + prep (blocks 512..4639) ----------
// scan: (b, chunk, d-pair): 4 x 64 x 512 threads, chunk = 32 t-steps.
// Loads all 32 xv first, then computes P/H and stores xb.
__global__ __launch_bounds__(256) void k_scanA(
    const float* __restrict__ x,
    const float* __restrict__ fgs, const float* __restrict__ fvs,
    const float* __restrict__ sgs, const float* __restrict__ svs,
    const float* __restrict__ fow, const float* __restrict__ sow,
    const float* __restrict__ mw,  const float* __restrict__ nw,
    float* __restrict__ PF, float* __restrict__ HF,
    float* __restrict__ PS, float* __restrict__ HS,
    unsigned short* __restrict__ xb,
    unsigned short* __restrict__ wcat, unsigned short* __restrict__ w2,
    float* __restrict__ rowsum) {
  if (blockIdx.x >= 512) {                 // ---- prep part ----
    int g = (blockIdx.x - 512) * 256 + threadIdx.x;   // 0..1056767
    if (g < 524288) {
      int i = g * 4;
      const float* src = (i < 1048576) ? (fow + i) : (sow + (i - 1048576));
      f32x4 v = *(const f32x4*)src;
      ushort4v o = { f2b(v.x), f2b(v.y), f2b(v.z), f2b(v.w) };
      *(ushort4v*)&wcat[i] = o;
    } else if (g < 1048576) {
      int i = (g - 524288) * 4;
      int m = i & 2047;
      f32x4 v = *(const f32x4*)&mw[i];
      f32x4 s = *(const f32x4*)&nw[m];
      ushort4v o = { f2b(v.x * s.x), f2b(v.y * s.y), f2b(v.z * s.z), f2b(v.w * s.w) };
      *(ushort4v*)&w2[i] = o;
    } else if (g < 1056768) {
      rowsum[g - 1048576] = 0.f;
    }
    return;
  }
  // ---- scan part ----
  int g = blockIdx.x * 256 + threadIdx.x;   // 0..131071
  int d0 = (g & 511) << 1;
  int rest = g >> 9;
  int chunk = rest & 63, b = rest >> 6;
  float fg0 = 1.f, fg1 = 1.f, fv0 = 1.f, fv1 = 1.f;
  float sg0 = 1.f, sg1 = 1.f, sv0 = 1.f, sv1 = 1.f;
#pragma unroll
  for (int i = 0; i < 5; ++i) {
    f32x2 a = *(const f32x2*)&fgs[i * 1024 + d0]; fg0 *= a.x; fg1 *= a.y;
    f32x2 bq = *(const f32x2*)&fvs[i * 1024 + d0]; fv0 *= bq.x; fv1 *= bq.y;
    f32x2 c = *(const f32x2*)&sgs[i * 1024 + d0]; sg0 *= c.x; sg1 *= c.y;
    f32x2 e = *(const f32x2*)&svs[i * 1024 + d0]; sv0 *= e.x; sv1 *= e.y;
  }
  size_t base = ((size_t)(b * 2048 + chunk * 32)) * 1024 + d0;
  // preload ALL t-steps (independent loads -> deep pipeline, no store waits)
  f32x2 xv[32];
#pragma unroll
  for (int t = 0; t < 32; ++t)
    xv[t] = *(const f32x2*)&x[base + (size_t)t * 1024];
  float pF0 = 1.f, hF0 = 0.f, pS0 = 1.f, hS0 = 0.f;
  float pF1 = 1.f, hF1 = 0.f, pS1 = 1.f, hS1 = 0.f;
#pragma unroll
  for (int t = 0; t < 32; ++t) {
    *(ushort2v*)&xb[base + (size_t)t * 1024] =
        ushort2v{f2b(xv[t].x), f2b(xv[t].y)};
    float fF0 = sigmoidf_(xv[t].x * fg0 + 0.5f);
    hF0 = fF0 * hF0 + (1.f - fF0) * (xv[t].x * fv0); pF0 *= fF0;
    float fS0 = 0.85f + 0.15f * sigmoidf_(xv[t].x * sg0 + 0.5f);
    hS0 = fS0 * hS0 + (1.f - fS0) * (xv[t].x * sv0); pS0 *= fS0;
    float fF1 = sigmoidf_(xv[t].y * fg1 + 0.5f);
    hF1 = fF1 * hF1 + (1.f - fF1) * (xv[t].y * fv1); pF1 *= fF1;
    float fS1 = 0.85f + 0.15f * sigmoidf_(xv[t].y * sg1 + 0.5f);
    hS1 = fS1 * hS1 + (1.f - fS1) * (xv[t].y * sv1); pS1 *= fS1;
  }
  int idx = (b * 64 + chunk) * 1024 + d0;
  *(f32x2*)&PF[idx] = f32x2{pF0, pF1};
  *(f32x2*)&HF[idx] = f32x2{hF0, hF1};
  *(f32x2*)&PS[idx] = f32x2{pS0, pS1};
  *(f32x2*)&HS[idx] = f32x2{hS0, hS1};
}

// ---------------- scanC: carry prefix + rescan (bf16 x) -> hcat ------------
__global__ __launch_bounds__(256) void k_scanC(
    const unsigned short* __restrict__ xb,
    const float* __restrict__ fgs, const float* __restrict__ fvs,
    const float* __restrict__ sgs, const float* __restrict__ svs,
    const float* __restrict__ PF, const float* __restrict__ HF,
    const float* __restrict__ PS, const float* __restrict__ HS,
    unsigned short* __restrict__ hcat) {
  int g = blockIdx.x * 256 + threadIdx.x;
  int d0 = (g & 511) << 1;
  int rest = g >> 9;
  int chunk = rest & 63, b = rest >> 6;   // block-uniform
  float fg0 = 1.f, fg1 = 1.f, fv0 = 1.f, fv1 = 1.f;
  float sg0 = 1.f, sg1 = 1.f, sv0 = 1.f, sv1 = 1.f;
#pragma unroll
  for (int i = 0; i < 5; ++i) {
    f32x2 a = *(const f32x2*)&fgs[i * 1024 + d0]; fg0 *= a.x; fg1 *= a.y;
    f32x2 bq = *(const f32x2*)&fvs[i * 1024 + d0]; fv0 *= bq.x; fv1 *= bq.y;
    f32x2 c = *(const f32x2*)&sgs[i * 1024 + d0]; sg0 *= c.x; sg1 *= c.y;
    f32x2 e = *(const f32x2*)&svs[i * 1024 + d0]; sv0 *= e.x; sv1 *= e.y;
  }
  // preload all xb t-steps (issued before any store; independent of prefix)
  size_t base = ((size_t)(b * 2048 + chunk * 32)) * 1024 + d0;
  ushort2v xv[32];
#pragma unroll
  for (int t = 0; t < 32; ++t)
    xv[t] = *(const ushort2v*)&xb[base + (size_t)t * 1024];
  // carry-in: combine chunk aggregates 0..chunk-1 (L2-resident), 4x batched
  float cF0 = 0.f, cF1 = 0.f, cS0 = 0.f, cS1 = 0.f;
  {
    int base_i = b * 64 * 1024 + d0;
    int c = 0;
    for (; c + 4 <= chunk; c += 4) {
      f32x2 pf[4], hf[4], ps[4], hs[4];
#pragma unroll
      for (int j = 0; j < 4; ++j) {
        int i = base_i + (c + j) * 1024;
        pf[j] = *(const f32x2*)&PF[i]; hf[j] = *(const f32x2*)&HF[i];
        ps[j] = *(const f32x2*)&PS[i]; hs[j] = *(const f32x2*)&HS[i];
      }
#pragma unroll
      for (int j = 0; j < 4; ++j) {
        cF0 = hf[j].x + pf[j].x * cF0; cF1 = hf[j].y + pf[j].y * cF1;
        cS0 = hs[j].x + ps[j].x * cS0; cS1 = hs[j].y + ps[j].y * cS1;
      }
    }
    for (; c < chunk; ++c) {
      int i = base_i + c * 1024;
      f32x2 pf = *(const f32x2*)&PF[i], hf = *(const f32x2*)&HF[i];
      f32x2 ps = *(const f32x2*)&PS[i], hs = *(const f32x2*)&HS[i];
      cF0 = hf.x + pf.x * cF0; cF1 = hf.y + pf.y * cF1;
      cS0 = hs.x + ps.x * cS0; cS1 = hs.y + ps.y * cS1;
    }
  }
  float pF0 = 1.f, hF0 = 0.f, pS0 = 1.f, hS0 = 0.f;
  float pF1 = 1.f, hF1 = 0.f, pS1 = 1.f, hS1 = 0.f;
#pragma unroll
  for (int t = 0; t < 32; ++t) {
    float x0 = b2f(xv[t].x), x1 = b2f(xv[t].y);
    float fF0 = sigmoidf_(x0 * fg0 + 0.5f);
    hF0 = fF0 * hF0 + (1.f - fF0) * (x0 * fv0); pF0 *= fF0;
    float fS0 = 0.85f + 0.15f * sigmoidf_(x0 * sg0 + 0.5f);
    hS0 = fS0 * hS0 + (1.f - fS0) * (x0 * sv0); pS0 *= fS0;
    float fF1 = sigmoidf_(x1 * fg1 + 0.5f);
    hF1 = fF1 * hF1 + (1.f - fF1) * (x1 * fv1); pF1 *= fF1;
    float fS1 = 0.85f + 0.15f * sigmoidf_(x1 * sg1 + 0.5f);
    hS1 = fS1 * hS1 + (1.f - fS1) * (x1 * sv1); pS1 *= fS1;
    size_t bt = (size_t)(b * 2048 + chunk * 32 + t);
    *(ushort2v*)&hcat[bt * 2048 + d0] =
        ushort2v{f2b(hF0 + pF0 * cF0), f2b(hF1 + pF1 * cF1)};
    *(ushort2v*)&hcat[bt * 2048 + 1024 + d0] =
        ushort2v{f2b(hS0 + pS0 * cS0), f2b(hS1 + pS1 * cS1)};
  }
}

// ------------------------- bf16 MFMA GEMM, 16x16x32, BK=64, swizzled -------
// C[m,n] = sum_k A[m,k]*B[n,k].  Block tile (2*WM)x(2*WN), 4 waves 2x2, each
// wave WMxWN of 16x16 MFMA tiles, BK=64 (2 sub-steps per barrier pair).
// LDS row stride 64 elts; 16B-chunk slot = chunk ^ (row&7): conflict-free.
// Grid 1D, XCD remap: col=(n>>3)&(2^CB-1); band=(n&7)|((n>>(3+CB))<<3).
// MODE 1: merged = bf16(sigmoid(C)*hcat); rowsum[m] += sum_n v^2 (atomic)
// MODE 2: out = rsqrt(rowsum[m]/2048 + 1e-6) * C
template <int WM, int WN, int MODE, int CB>
__global__ __launch_bounds__(256, 4) void k_gemm(
    const unsigned short* __restrict__ A, const unsigned short* __restrict__ B,
    const int K,
    const unsigned short* __restrict__ hcat, unsigned short* __restrict__ merged,
    float* __restrict__ rowsum, float* __restrict__ out) {
  constexpr int BM = 2 * WM, BN = 2 * WN;
  constexpr int RA = BM / 32, RB = BN / 32;   // cp16 rounds (8 rows each)
  constexpr int AM = WM / 16, BT = WN / 16;
  __shared__ __align__(16) unsigned short sA[BM * 64];
  __shared__ __align__(16) unsigned short sB[BN * 64];
  const int tid = threadIdx.x, wv = tid >> 6, ln = tid & 63;
  const int n_ = blockIdx.x;
  const int col = (n_ >> 3) & ((1 << CB) - 1);
  const int band = (n_ & 7) | ((n_ >> (3 + CB)) << 3);
  const int bm = band * BM, bn = col * BN;

  const int srow = ln >> 3;                       // 0..7 within round
  const int clog = (ln & 7) ^ srow;               // swizzled logical chunk
  const unsigned short* gA[RA]; unsigned short* lA[RA];
  const unsigned short* gB[RB]; unsigned short* lB[RB];
#pragma unroll
  for (int j = 0; j < RA; ++j) {
    const int R0 = wv * (BM / 4) + j * 8;
    gA[j] = A + (size_t)(bm + R0 + srow) * K + clog * 8;
    lA[j] = &sA[R0 * 64 + ln * 8];
  }
#pragma unroll
  for (int j = 0; j < RB; ++j) {
    const int R0 = wv * (BN / 4) + j * 8;
    gB[j] = B + (size_t)(bn + R0 + srow) * K + clog * 8;
    lB[j] = &sB[R0 * 64 + ln * 8];
  }

  const int fr = ln & 15, fq = ln >> 4;           // frag row, chunk base 0..3
  const int wm = (wv >> 1) * WM, wn = (wv & 1) * WN;

  f32x4 acc[AM][BT];
  const f32x4 z4 = {0.f, 0.f, 0.f, 0.f};
#pragma unroll
  for (int i = 0; i < AM; ++i)
#pragma unroll
    for (int j = 0; j < BT; ++j) acc[i][j] = z4;

  for (int k0 = 0; k0 < K; k0 += 64) {
#pragma unroll
    for (int j = 0; j < RA; ++j) cp16(gA[j] + k0, lA[j]);
#pragma unroll
    for (int j = 0; j < RB; ++j) cp16(gB[j] + k0, lB[j]);
    __syncthreads();
#pragma unroll
    for (int sub = 0; sub < 2; ++sub) {
      short8 af[AM], bf[BT];
#pragma unroll
      for (int mi = 0; mi < AM; ++mi) {
        const int row = wm + mi * 16 + fr;
        const int slot = (fq + sub * 4) ^ (row & 7);
        af[mi] = *(const short8*)&sA[row * 64 + slot * 8];
      }
#pragma unroll
      for (int ni = 0; ni < BT; ++ni) {
        const int row = wn + ni * 16 + fr;
        const int slot = (fq + sub * 4) ^ (row & 7);
        bf[ni] = *(const short8*)&sB[row * 64 + slot * 8];
      }
#pragma unroll
      for (int mi = 0; mi < AM; ++mi)
#pragma unroll
        for (int ni = 0; ni < BT; ++ni)
          acc[mi][ni] = __builtin_amdgcn_mfma_f32_16x16x32_bf16(
              af[mi], bf[ni], acc[mi][ni], 0, 0, 0);
    }
    __syncthreads();
  }

  // C/D layout: col = lane&15, row = (lane>>4)*4 + reg   [verified m89/m91]
  const int er0 = fq * 4;
  if (MODE == 1) {
#pragma unroll
    for (int mi = 0; mi < AM; ++mi) {
#pragma unroll
      for (int r = 0; r < 4; ++r) {
        const int m = bm + wm + mi * 16 + er0 + r;
        float s = 0.f;
#pragma unroll
        for (int ni = 0; ni < BT; ++ni) {
          const int n = bn + wn + ni * 16 + fr;
          const size_t idx = (size_t)m * 2048 + n;
          float v = sigmoidf_(acc[mi][ni][r]) * b2f(hcat[idx]);
          merged[idx] = f2b(v);
          s += v * v;
        }
        s += __shfl_xor(s, 1); s += __shfl_xor(s, 2);
        s += __shfl_xor(s, 4); s += __shfl_xor(s, 8);
        if (fr == 0) atomicAdd(&rowsum[m], s);
      }
    }
  } else {
#pragma unroll
    for (int mi = 0; mi < AM; ++mi) {
#pragma unroll
      for (int r = 0; r < 4; ++r) {
        const int m = bm + wm + mi * 16 + er0 + r;
        const float rf = rsqrtf(rowsum[m] * (1.0f / 2048.0f) + 1e-6f);
#pragma unroll
        for (int ni = 0; ni < BT; ++ni) {
          const int n = bn + wn + ni * 16 + fr;
          out[(size_t)m * 1024 + n] = rf * acc[mi][ni][r];
        }
      }
    }
  }
}

// ---------------------------------------------------------------------------
extern "C" void kernel_launch(void* const* d_in, const int* in_sizes, int n_in,
                              void* d_out, int out_size, void* d_ws, size_t ws_size,
                              hipStream_t stream) {
  const float* x   = (const float*)d_in[0];
  const float* fgs = (const float*)d_in[1];
  const float* fvs = (const float*)d_in[2];
  const float* fow = (const float*)d_in[3];
  const float* sgs = (const float*)d_in[4];
  const float* svs = (const float*)d_in[5];
  const float* sow = (const float*)d_in[6];
  const float* mw  = (const float*)d_in[7];
  const float* nw  = (const float*)d_in[8];
  float* out = (float*)d_out;

  char* ws = (char*)d_ws;
  float* rowsum = (float*)(ws + 0);                         // 32 KB
  unsigned short* xb   = (unsigned short*)(ws + 32768);     // 16 MB
  unsigned short* wcat = (unsigned short*)(ws + 16809984);  // 4 MB
  unsigned short* w2   = (unsigned short*)(ws + 21004288);  // 4 MB
  unsigned short* hcat = (unsigned short*)(ws + 25198592);  // 32 MB
  unsigned short* mg   = (unsigned short*)(ws + 58753024);  // 32 MB (end ~92MB)
  // P/H (1 MB each) alias the mg region: P/H are dead before GEMM1 writes mg.
  float* PF = (float*)(ws + 58753024);
  float* HF = (float*)(ws + 58753024 + 1 * 1048576);
  float* PS = (float*)(ws + 58753024 + 2 * 1048576);
  float* HS = (float*)(ws + 58753024 + 3 * 1048576);

  // scan (blocks 0..511) + weight prep (blocks 512..4639)
  k_scanA<<<4640, 256, 0, stream>>>(x, fgs, fvs, sgs, svs, fow, sow, mw, nw,
                                    PF, HF, PS, HS, xb, wcat, w2, rowsum);
  k_scanC<<<512, 256, 0, stream>>>(xb, fgs, fvs, sgs, svs, PF, HF, PS, HS,
                                   hcat);
  // GEMM1: M=8192, N=2048, K=1024; tile 128x128; 64 bands x 16 cols
  k_gemm<64, 64, 1, 4><<<1024, 256, 0, stream>>>(
      xb, wcat, 1024, hcat, mg, rowsum, nullptr);
  // GEMM2: M=8192, N=1024, K=2048; tile 64x128; 128 bands x 8 cols
  k_gemm<32, 64, 2, 3><<<1024, 256, 0, stream>>>(
      mg, w2, 2048, nullptr, nullptr, rowsum, out);
}